// Round 6
// baseline (1108.889 us; speedup 1.0000x reference)
//
#include <hip/hip_runtime.h>
#include <hip/hip_bf16.h>

#define NN 4096
#define NI 16384   // N*I
#define HH 32

typedef __attribute__((ext_vector_type(8))) short short8;
typedef __attribute__((ext_vector_type(4))) float f32x4;
typedef unsigned long long u64;

union bfrag { short8 s8; u64 q[2]; };

__device__ __forceinline__ short f2bs(float f) {
  __hip_bfloat16 b = __float2bfloat16(f);
  return *(short*)&b;
}

__device__ __forceinline__ unsigned pack2(float lo, float hi) {
  return (unsigned)(unsigned short)f2bs(lo) |
         ((unsigned)(unsigned short)f2bs(hi) << 16);
}

// zT B-fragment layout: element z[n][h] at short index
//   ((hb*128 + kb)*64 + hl + 16*oct)*8 + j  (hb=h>>4, hl=h&15, kb=n>>5, oct=(n>>3)&3, j=n&7)
__device__ __forceinline__ long zt_idx(int n, int h) {
  const int hb = h >> 4, hl = h & 15;
  const int kb = n >> 5, oct = (n >> 3) & 3, j = n & 7;
  return ((long)(hb * 128 + kb) * 64 + hl + 16 * oct) * 8 + j;
}

// ---------------- natural cubic spline -> dX/dt at s=0, 0.5, 1 ----------------
// Also zero-inits the producer counters (replay-safe: reruns every graph replay).
__global__ void k_spline(const float* __restrict__ x,
                         float* __restrict__ dx0, float* __restrict__ dxh,
                         float* __restrict__ dx1, unsigned* __restrict__ bar) {
  if (blockIdx.x == 0) {
    for (int i = threadIdx.x; i < 576; i += 256) bar[i] = 0u;
    // counters: cnt[g] at bar[g*32], g=0..15 (one per 256-row K-group)
  }
  const int c = blockIdx.x * 256 + threadIdx.x;
  float y[16];
#pragma unroll
  for (int t = 0; t < 16; ++t) y[t] = x[t * NI + c];
  float cp[15], dp[15], M[16];
  cp[1] = 0.25f;
  dp[1] = (6.f * (y[2] - 2.f * y[1] + y[0])) * 0.25f;
#pragma unroll
  for (int i = 2; i <= 14; ++i) {
    float ri = 6.f * (y[i + 1] - 2.f * y[i] + y[i - 1]);
    float inv = 1.f / (4.f - cp[i - 1]);
    cp[i] = inv;
    dp[i] = (ri - dp[i - 1]) * inv;
  }
  M[0] = 0.f; M[15] = 0.f;
  M[14] = dp[14];
#pragma unroll
  for (int i = 13; i >= 1; --i) M[i] = dp[i] - cp[i] * M[i + 1];
#pragma unroll
  for (int i = 0; i < 15; ++i) {
    float b = (y[i + 1] - y[i]) - (2.f * M[i] + M[i + 1]) * (1.f / 6.f);
    float cc = 0.5f * M[i];
    float dd = (M[i + 1] - M[i]) * (1.f / 6.f);
    dx0[i * NI + c] = b;
    dxh[i * NI + c] = b + cc + 0.75f * dd;
    dx1[i * NI + c] = b + 2.f * cc + 3.f * dd;
  }
}

// ---- decoder for 16 rows: 256 lanes' worth of work, caller picks the threads.
// q in [0,256): rr = q>>4 (row), jj = q&15 (hidden unit); 16-lane shfl reduce.
__device__ __forceinline__ void dec_rows(const float* zsrc /*[16][33]*/,
                                         const float* Wd1s /*[32][16]*/,
                                         const float* dsm, float* op,
                                         int r0, int q) {
  const int rr = q >> 4, jj = q & 15;
  float hv = dsm[jj];
#pragma unroll
  for (int hh = 0; hh < 32; ++hh) hv = fmaf(zsrc[rr * 33 + hh], Wd1s[hh * 16 + jj], hv);
  float val = fmaxf(hv, 0.f) * dsm[16 + jj];
#pragma unroll
  for (int off = 1; off < 16; off <<= 1) val += __shfl_xor(val, off, 64);
  if (jj == 0)
    __hip_atomic_store(op + r0 + rr, 1.f / (1.f + expf(-(dsm[32] + val))),
                       __ATOMIC_RELAXED, __HIP_MEMORY_SCOPE_AGENT);
}

// ---------------- persistent full-integration kernel ----------------
// 256 blocks x 1024 threads (16 waves), 1 block/CU (plain launch: grid == CU
// count with 1024-thread blocks -> all blocks dispatched immediately).
// Sync: fine-grained producer counters, one per 256-row K-group.
//   Producer: each compute wave w<8 packs ITS OWN 2 rows from registers
//   (shfl + 1 u32 WT store/lane<32), drains its own vmcnt, adds to cnt.
//   Consumer: wave w polls cnt[w] >= 128*e, then ingests its K-slice.
// 3 barriers/epoch; decoder runs on idle waves 8-11 one epoch late.
__global__ __launch_bounds__(1024, 4) void k_ode(
    const float* __restrict__ adj, const float* __restrict__ x,
    const float* __restrict__ dx0, const float* __restrict__ dxh,
    const float* __restrict__ dx1,
    const float* __restrict__ We, const float* __restrict__ be,
    const float* __restrict__ Wg, const float* __restrict__ bg,
    const float* __restrict__ Wt, const float* __restrict__ bt,
    const float* __restrict__ Wp, const float* __restrict__ bp,
    const float* __restrict__ Wd1, const float* __restrict__ bd1,
    const float* __restrict__ Wd2, const float* __restrict__ bd2,
    short* __restrict__ zTa, short* __restrict__ zTb,
    unsigned* __restrict__ bar, float* __restrict__ out) {
  __shared__ float red2[16][34][17];   // cross-wave MFMA partials; stride 578≡2 mod 32
  __shared__ float zn_s[16][33];
  __shared__ float h_s[16][33];
  __shared__ float ze_s[16][33];       // z at which vf is evaluated (f32)
  __shared__ float zb_s[16][33];       // RK4 base z
  __shared__ float ka_s[16][33];       // k1 + 2k2 + 2k3 accumulator
  __shared__ float Wg_s[32][32];
  __shared__ float Wt_s[32][32];
  __shared__ float Wp_s[32][136];      // row stride 544 B, float4-readable
  __shared__ float Wd1_s[32][16];
  __shared__ float bgt_s[32];
  __shared__ float bp_s[128];
  __shared__ float dsm[33];            // b_d1[0:16], W_d2[16:32], b_d2[32]

  const int tid = threadIdx.x;
  const int lane = tid & 63;
  const int w = tid >> 6;              // wave 0..15, K-slice [w*256, +256)
  const int bid = blockIdx.x;
  const int r0 = bid * 16;
  const int fr = lane & 15, oct = lane >> 4;
  unsigned* cnt_mine = bar + (bid >> 4) * 32;   // this block's K-group counter
  unsigned* cnt_wave = bar + w * 32;            // counter this wave consumes

  // ---- adj -> registers, bf16 A-fragment order (once, ~64 MB grid-wide) ----
  short8 av[8];
  {
    const float* arow = adj + (long)(r0 + fr) * NN + w * 256 + oct * 8;
#pragma unroll
    for (int i = 0; i < 8; ++i) {
      const float4 u0 = *(const float4*)(arow + i * 32);
      const float4 u1 = *(const float4*)(arow + i * 32 + 4);
      short8 rf;
      rf[0] = f2bs(u0.x); rf[1] = f2bs(u0.y); rf[2] = f2bs(u0.z); rf[3] = f2bs(u0.w);
      rf[4] = f2bs(u1.x); rf[5] = f2bs(u1.y); rf[6] = f2bs(u1.z); rf[7] = f2bs(u1.w);
      av[i] = rf;
    }
  }

  // ---- stage weights into LDS (once for all 60 evals) ----
  Wg_s[tid >> 5][tid & 31] = Wg[tid];
  Wt_s[tid >> 5][tid & 31] = Wt[tid];
#pragma unroll
  for (int idx = tid; idx < 4096; idx += 1024)
    Wp_s[idx >> 7][idx & 127] = Wp[idx];
  if (tid < 512) Wd1_s[tid >> 4][tid & 15] = Wd1[tid];
  if (tid < 32) bgt_s[tid] = bg[tid] + bt[tid];
  if (tid < 128) bp_s[tid] = bp[tid];
  if (tid < 16) { dsm[tid] = bd1[tid]; dsm[16 + tid] = Wd2[tid]; }
  if (tid == 0) dsm[32] = bd2[0];

  // ---- encoder: z0 for this block's 16 rows ----
  const int r = (tid >> 5) & 15, c = tid & 31;
  float zenc = 0.f;
  if (tid < 512) {
    const int n = r0 + r;
    float acc = be[c];
#pragma unroll
    for (int i = 0; i < 4; ++i) acc = fmaf(x[n * 4 + i], We[i * 32 + c], acc);
    zb_s[r][c] = acc;
    ze_s[r][c] = acc;
    zenc = acc;
  }
  __syncthreads();

  // ---- publish version 1 (z0): each wave w<8 packs its own 2 rows ----
  if (tid < 512) {
    const float zhi = __shfl_down(zenc, 32);     // lane L: row 2w+1, col L
    if (lane < 32)
      __hip_atomic_store((unsigned*)zTa + (zt_idx(r0 + 2 * w, lane) >> 1),
                         pack2(zenc, zhi),
                         __ATOMIC_RELAXED, __HIP_MEMORY_SCOPE_AGENT);
    if (lane == 0) {
      asm volatile("s_waitcnt vmcnt(0)" ::: "memory");   // wave-own store drain
      __hip_atomic_fetch_add(cnt_mine, 1u, __ATOMIC_RELAXED, __HIP_MEMORY_SCOPE_AGENT);
    }
  }
  if (tid < 256) dec_rows(&zb_s[0][0], &Wd1_s[0][0], dsm, out, r0, tid);  // t=0

  // ---- main integration: epochs e = 1..60 (t = (e-1)/4, substep j = 1..4) ----
  for (int e = 1; e <= 60; ++e) {
    const int tt = (e - 1) >> 2, j = ((e - 1) & 3) + 1;
    const float* dxp = (j == 1) ? dx0 + tt * NI
                     : (j == 4) ? dx1 + tt * NI : dxh + tt * NI;
    const short* zi = (e & 1) ? zTa : zTb;
    short* zo = (e & 1) ? zTb : zTa;

    // dx row: read-only precomputed data; issue before the poll
    float4 dxv;
    if (tid < 512) dxv = *(const float4*)(dxp + (long)(r0 + r) * 4);

    // ---- per-wave poll: wait for this wave's producer K-group (128·e adds) ----
    unsigned cv = 0;
    if (lane == 0) {
      cv = __hip_atomic_load(cnt_wave, __ATOMIC_RELAXED, __HIP_MEMORY_SCOPE_AGENT);
      while (cv < (unsigned)(128 * e)) {
        __builtin_amdgcn_s_sleep(1);
        cv = __hip_atomic_load(cnt_wave, __ATOMIC_RELAXED, __HIP_MEMORY_SCOPE_AGENT);
      }
    }
    cv = (unsigned)__builtin_amdgcn_readfirstlane((int)cv);

    // ---- MFMA: zn = adj @ z over K-slice [w*256,+256).
    // (cv>>31)==0 at runtime; forces the loads to depend on the observed count.
    f32x4 a0 = {0.f, 0.f, 0.f, 0.f}, a1 = {0.f, 0.f, 0.f, 0.f};
    const u64* bq = (const u64*)zi + (size_t)w * 1024 + (lane << 1) + (cv >> 31);
    bfrag bf[8];
#pragma unroll
    for (int i = 0; i < 8; ++i) {
      bf[i].q[0] = __hip_atomic_load(bq + i * 128,
                                     __ATOMIC_RELAXED, __HIP_MEMORY_SCOPE_AGENT);
      bf[i].q[1] = __hip_atomic_load(bq + i * 128 + 1,
                                     __ATOMIC_RELAXED, __HIP_MEMORY_SCOPE_AGENT);
    }
#pragma unroll
    for (int i = 0; i < 8; ++i)
      a0 = __builtin_amdgcn_mfma_f32_16x16x32_bf16(av[i], bf[i].s8, a0, 0, 0, 0);
#pragma unroll
    for (int i = 0; i < 8; ++i) {
      bf[i].q[0] = __hip_atomic_load(bq + 16384 + i * 128,
                                     __ATOMIC_RELAXED, __HIP_MEMORY_SCOPE_AGENT);
      bf[i].q[1] = __hip_atomic_load(bq + 16384 + i * 128 + 1,
                                     __ATOMIC_RELAXED, __HIP_MEMORY_SCOPE_AGENT);
    }
#pragma unroll
    for (int i = 0; i < 8; ++i)
      a1 = __builtin_amdgcn_mfma_f32_16x16x32_bf16(av[i], bf[i].s8, a1, 0, 0, 0);

    {
      const int crow = (lane >> 4) * 4, ccol = lane & 15;  // C/D: col=lane&15
#pragma unroll
      for (int q = 0; q < 4; ++q) {
        red2[crow + q][ccol][w] = a0[q];
        red2[crow + q][ccol + 16][w] = a1[q];
      }
    }
    __syncthreads();                       // B1: red2 complete

    // ---- cross-wave K-reduction (waves 0-7); decoder on waves 8-11 ----
    if (tid < 512) {
      float zn = 0.f;
#pragma unroll
      for (int q = 0; q < 16; ++q) zn += red2[r][c][q];
      zn_s[r][c] = zn;
    } else if (j == 1 && e > 1 && tid < 768) {
      // zb_s holds z_tt (stable this epoch; j==1 einsum doesn't write it)
      dec_rows(&zb_s[0][0], &Wd1_s[0][0], dsm, out + tt * NN, r0, tid - 512);
    }
    __syncthreads();                       // B2: zn_s complete, red2 free

    // ---- h = relu(zn@Wg + ze@Wt + bg + bt) ----
    if (tid < 512) {
      float hv = bgt_s[c];
#pragma unroll
      for (int kk = 0; kk < 32; ++kk)
        hv = fmaf(zn_s[r][kk], Wg_s[kk][c], fmaf(ze_s[r][kk], Wt_s[kk][c], hv));
      h_s[r][c] = fmaxf(hv, 0.f);
    }
    __syncthreads();                       // B3: h_s complete

    // ---- sens/einsum + RK4 state update + per-wave publish (no barrier) ----
    if (tid < 512) {
      float s0 = bp_s[c * 4], s1 = bp_s[c * 4 + 1];
      float s2 = bp_s[c * 4 + 2], s3 = bp_s[c * 4 + 3];
#pragma unroll
      for (int hp = 0; hp < 32; ++hp) {
        const float4 wv = *(const float4*)&Wp_s[hp][c * 4];
        const float hr = h_s[r][hp];
        s0 = fmaf(hr, wv.x, s0);
        s1 = fmaf(hr, wv.y, s1);
        s2 = fmaf(hr, wv.z, s2);
        s3 = fmaf(hr, wv.w, s3);
      }
      const float kv = s0 * dxv.x + s1 * dxv.y + s2 * dxv.z + s3 * dxv.w;
      float zev;
      if (j == 1)      { ka_s[r][c] = kv;            zev = zb_s[r][c] + 0.5f * kv; }
      else if (j == 2) { ka_s[r][c] += 2.f * kv;     zev = zb_s[r][c] + 0.5f * kv; }
      else if (j == 3) { ka_s[r][c] += 2.f * kv;     zev = zb_s[r][c] + kv; }
      else { zev = zb_s[r][c] + (ka_s[r][c] + kv) * (1.f / 6.f); zb_s[r][c] = zev; }
      ze_s[r][c] = zev;

      // publish this wave's 2 rows straight from registers
      const float zhi = __shfl_down(zev, 32);
      if (lane < 32)
        __hip_atomic_store((unsigned*)zo + (zt_idx(r0 + 2 * w, lane) >> 1),
                           pack2(zev, zhi),
                           __ATOMIC_RELAXED, __HIP_MEMORY_SCOPE_AGENT);
      if (lane == 0) {
        asm volatile("s_waitcnt vmcnt(0)" ::: "memory");
        __hip_atomic_fetch_add(cnt_mine, 1u, __ATOMIC_RELAXED, __HIP_MEMORY_SCOPE_AGENT);
      }
    }
  }

  // ---- final decode: z_15 ----
  __syncthreads();
  if (tid < 256) dec_rows(&zb_s[0][0], &Wd1_s[0][0], dsm, out + 15 * NN, r0, tid);
}

extern "C" void kernel_launch(void* const* d_in, const int* in_sizes, int n_in,
                              void* d_out, int out_size, void* d_ws, size_t ws_size,
                              hipStream_t stream) {
  (void)in_sizes; (void)n_in; (void)out_size; (void)ws_size;
  const float* x      = (const float*)d_in[0];
  const float* adj    = (const float*)d_in[1];
  const float* W_enc  = (const float*)d_in[2];
  const float* b_enc  = (const float*)d_in[3];
  const float* W_gcn  = (const float*)d_in[4];
  const float* b_gcn  = (const float*)d_in[5];
  const float* W_time = (const float*)d_in[6];
  const float* b_time = (const float*)d_in[7];
  const float* W_proj = (const float*)d_in[8];
  const float* b_proj = (const float*)d_in[9];
  const float* W_d1   = (const float*)d_in[10];
  const float* b_d1   = (const float*)d_in[11];
  const float* W_d2   = (const float*)d_in[12];
  const float* b_d2   = (const float*)d_in[13];
  float* out = (float*)d_out;

  float* dx0 = (float*)d_ws;
  float* dxh = dx0 + 15 * NI;
  float* dx1 = dxh + 15 * NI;
  short* zTa = (short*)(dx1 + 15 * NI);
  short* zTb = zTa + HH * NN;
  unsigned* bar = (unsigned*)(zTb + HH * NN);   // 576 u32 of counter state

  k_spline<<<64, 256, 0, stream>>>(x, dx0, dxh, dx1, bar);

  // Plain launch (no cooperative path): 256 blocks x 1024 threads on 256 CUs
  // = exactly 1 block/CU; all blocks are dispatched immediately, so the
  // producer-counter scheme is safe without cooperative-launch machinery.
  k_ode<<<256, 1024, 0, stream>>>(adj, x, dx0, dxh, dx1, W_enc, b_enc,
                                  W_gcn, b_gcn, W_time, b_time, W_proj, b_proj,
                                  W_d1, b_d1, W_d2, b_d2, zTa, zTb, bar, out);
}

// Round 7
// 874.439 us; speedup vs baseline: 1.2681x; 1.2681x over previous
//
#include <hip/hip_runtime.h>
#include <hip/hip_bf16.h>

#define NN 4096
#define NI 16384   // N*I
#define HH 32

typedef __attribute__((ext_vector_type(8))) short short8;
typedef __attribute__((ext_vector_type(4))) float f32x4;
typedef unsigned long long u64;

union bfrag { short8 s8; u64 q[2]; };

__device__ __forceinline__ short f2bs(float f) {
  __hip_bfloat16 b = __float2bfloat16(f);
  return *(short*)&b;
}

__device__ __forceinline__ unsigned pack2(float lo, float hi) {
  return (unsigned)(unsigned short)f2bs(lo) |
         ((unsigned)(unsigned short)f2bs(hi) << 16);
}

// zT B-fragment layout: element z[n][h] at short index
//   ((hb*128 + kb)*64 + hl + 16*oct)*8 + j  (hb=h>>4, hl=h&15, kb=n>>5, oct=(n>>3)&3, j=n&7)
__device__ __forceinline__ long zt_idx(int n, int h) {
  const int hb = h >> 4, hl = h & 15;
  const int kb = n >> 5, oct = (n >> 3) & 3, j = n & 7;
  return ((long)(hb * 128 + kb) * 64 + hl + 16 * oct) * 8 + j;
}

// ---------------- natural cubic spline -> dX/dt at s=0, 0.5, 1 ----------------
// Also zero-inits the per-block flags (replay-safe: reruns every graph replay).
__global__ void k_spline(const float* __restrict__ x,
                         float* __restrict__ dx0, float* __restrict__ dxh,
                         float* __restrict__ dx1, unsigned* __restrict__ bar) {
  if (blockIdx.x == 0) {
    for (int i = threadIdx.x; i < 512; i += 256) bar[i] = 0u;
    // flag[bid] at bar[bid], bid=0..255; group w's flags = bar[16w..16w+15] (one line)
  }
  const int c = blockIdx.x * 256 + threadIdx.x;
  float y[16];
#pragma unroll
  for (int t = 0; t < 16; ++t) y[t] = x[t * NI + c];
  float cp[15], dp[15], M[16];
  cp[1] = 0.25f;
  dp[1] = (6.f * (y[2] - 2.f * y[1] + y[0])) * 0.25f;
#pragma unroll
  for (int i = 2; i <= 14; ++i) {
    float ri = 6.f * (y[i + 1] - 2.f * y[i] + y[i - 1]);
    float inv = 1.f / (4.f - cp[i - 1]);
    cp[i] = inv;
    dp[i] = (ri - dp[i - 1]) * inv;
  }
  M[0] = 0.f; M[15] = 0.f;
  M[14] = dp[14];
#pragma unroll
  for (int i = 13; i >= 1; --i) M[i] = dp[i] - cp[i] * M[i + 1];
#pragma unroll
  for (int i = 0; i < 15; ++i) {
    float b = (y[i + 1] - y[i]) - (2.f * M[i] + M[i + 1]) * (1.f / 6.f);
    float cc = 0.5f * M[i];
    float dd = (M[i + 1] - M[i]) * (1.f / 6.f);
    dx0[i * NI + c] = b;
    dxh[i * NI + c] = b + cc + 0.75f * dd;
    dx1[i * NI + c] = b + 2.f * cc + 3.f * dd;
  }
}

// ---- decoder for 16 rows: 256 lanes' worth of work, caller picks the threads.
// q in [0,256): rr = q>>4 (row), jj = q&15 (hidden unit); 16-lane shfl reduce.
__device__ __forceinline__ void dec_rows(const float* zsrc /*[16][33]*/,
                                         const float* Wd1s /*[32][16]*/,
                                         const float* dsm, float* op,
                                         int r0, int q) {
  const int rr = q >> 4, jj = q & 15;
  float hv = dsm[jj];
#pragma unroll
  for (int hh = 0; hh < 32; ++hh) hv = fmaf(zsrc[rr * 33 + hh], Wd1s[hh * 16 + jj], hv);
  float val = fmaxf(hv, 0.f) * dsm[16 + jj];
#pragma unroll
  for (int off = 1; off < 16; off <<= 1) val += __shfl_xor(val, off, 64);
  if (jj == 0)
    __hip_atomic_store(op + r0 + rr, 1.f / (1.f + expf(-(dsm[32] + val))),
                       __ATOMIC_RELAXED, __HIP_MEMORY_SCOPE_AGENT);
}

// ---------------- persistent full-integration kernel ----------------
// 256 blocks x 1024 threads (16 waves), 1 block/CU, COOPERATIVE (plain launch
// risks preemption of the spin loop: r6 showed a 21.5 ms time-slice stall).
// Sync (zero global RMW):
//   Producer: each compute wave w<8 packs its 2 rows from registers (WT u32
//   atomics), drains its own vmcnt, LDS-atomicAdd; LAST wave WT-stores
//   flag[bid] = version. 256 independent flag dwords, stored in parallel.
//   Consumer: wave w polls the 16 flags of blocks 16w..16w+15 (one 64 B
//   line; lane<16 atomic loads + __all), then ingests its K-slice.
// Safety: flag=e => that block passed B3(e-1) => all its waves' reads of
// version e-1 done. Each block's 16 waves collectively poll all 256 flags
// before B1(e), so einsum-phase writes over version e-1 are race-free.
__global__ __launch_bounds__(1024, 4) void k_ode(
    const float* __restrict__ adj, const float* __restrict__ x,
    const float* __restrict__ dx0, const float* __restrict__ dxh,
    const float* __restrict__ dx1,
    const float* __restrict__ We, const float* __restrict__ be,
    const float* __restrict__ Wg, const float* __restrict__ bg,
    const float* __restrict__ Wt, const float* __restrict__ bt,
    const float* __restrict__ Wp, const float* __restrict__ bp,
    const float* __restrict__ Wd1, const float* __restrict__ bd1,
    const float* __restrict__ Wd2, const float* __restrict__ bd2,
    short* __restrict__ zTa, short* __restrict__ zTb,
    unsigned* __restrict__ bar, float* __restrict__ out) {
  __shared__ float red2[16][34][17];   // cross-wave MFMA partials; stride 578≡2 mod 32
  __shared__ float zn_s[16][33];
  __shared__ float h_s[16][33];
  __shared__ float ze_s[16][33];       // z at which vf is evaluated (f32)
  __shared__ float zb_s[16][33];       // RK4 base z
  __shared__ float ka_s[16][33];       // k1 + 2k2 + 2k3 accumulator
  __shared__ float Wg_s[32][32];
  __shared__ float Wt_s[32][32];
  __shared__ float Wp_s[32][136];      // row stride 544 B, float4-readable
  __shared__ float Wd1_s[32][16];
  __shared__ float bgt_s[32];
  __shared__ float bp_s[128];
  __shared__ float dsm[33];            // b_d1[0:16], W_d2[16:32], b_d2[32]
  __shared__ unsigned lcnt;            // monotonic publish counter (8 adds/epoch)

  const int tid = threadIdx.x;
  const int lane = tid & 63;
  const int w = tid >> 6;              // wave 0..15, K-slice [w*256, +256)
  const int bid = blockIdx.x;
  const int r0 = bid * 16;
  const int fr = lane & 15, oct = lane >> 4;

  // ---- adj -> registers, bf16 A-fragment order (once, ~64 MB grid-wide) ----
  short8 av[8];
  {
    const float* arow = adj + (long)(r0 + fr) * NN + w * 256 + oct * 8;
#pragma unroll
    for (int i = 0; i < 8; ++i) {
      const float4 u0 = *(const float4*)(arow + i * 32);
      const float4 u1 = *(const float4*)(arow + i * 32 + 4);
      short8 rf;
      rf[0] = f2bs(u0.x); rf[1] = f2bs(u0.y); rf[2] = f2bs(u0.z); rf[3] = f2bs(u0.w);
      rf[4] = f2bs(u1.x); rf[5] = f2bs(u1.y); rf[6] = f2bs(u1.z); rf[7] = f2bs(u1.w);
      av[i] = rf;
    }
  }

  // ---- stage weights into LDS (once for all 60 evals) ----
  Wg_s[tid >> 5][tid & 31] = Wg[tid];
  Wt_s[tid >> 5][tid & 31] = Wt[tid];
#pragma unroll
  for (int idx = tid; idx < 4096; idx += 1024)
    Wp_s[idx >> 7][idx & 127] = Wp[idx];
  if (tid < 512) Wd1_s[tid >> 4][tid & 15] = Wd1[tid];
  if (tid < 32) bgt_s[tid] = bg[tid] + bt[tid];
  if (tid < 128) bp_s[tid] = bp[tid];
  if (tid < 16) { dsm[tid] = bd1[tid]; dsm[16 + tid] = Wd2[tid]; }
  if (tid == 0) { dsm[32] = bd2[0]; lcnt = 0u; }

  // ---- encoder: z0 for this block's 16 rows ----
  const int r = (tid >> 5) & 15, c = tid & 31;
  float zenc = 0.f;
  if (tid < 512) {
    const int n = r0 + r;
    float acc = be[c];
#pragma unroll
    for (int i = 0; i < 4; ++i) acc = fmaf(x[n * 4 + i], We[i * 32 + c], acc);
    zb_s[r][c] = acc;
    ze_s[r][c] = acc;
    zenc = acc;
  }
  __syncthreads();

  // ---- publish version 1 (z0): each wave w<8 packs its own 2 rows;
  // last wave (LDS count==8) stores flag[bid]=1 ----
  if (tid < 512) {
    const float zhi = __shfl_down(zenc, 32);     // lane L: row 2w+1, col L
    if (lane < 32)
      __hip_atomic_store((unsigned*)zTa + (zt_idx(r0 + 2 * w, lane) >> 1),
                         pack2(zenc, zhi),
                         __ATOMIC_RELAXED, __HIP_MEMORY_SCOPE_AGENT);
    if (lane == 0) {
      asm volatile("s_waitcnt vmcnt(0)" ::: "memory");   // wave-own store drain
      const unsigned old = atomicAdd(&lcnt, 1u);
      if (old == 7u)
        __hip_atomic_store(bar + bid, 1u,
                           __ATOMIC_RELAXED, __HIP_MEMORY_SCOPE_AGENT);
    }
  }
  if (tid < 256) dec_rows(&zb_s[0][0], &Wd1_s[0][0], dsm, out, r0, tid);  // t=0

  // ---- main integration: epochs e = 1..60 (t = (e-1)/4, substep j = 1..4) ----
  for (int e = 1; e <= 60; ++e) {
    const int tt = (e - 1) >> 2, j = ((e - 1) & 3) + 1;
    const float* dxp = (j == 1) ? dx0 + tt * NI
                     : (j == 4) ? dx1 + tt * NI : dxh + tt * NI;
    const short* zi = (e & 1) ? zTa : zTb;
    short* zo = (e & 1) ? zTb : zTa;

    // dx row: read-only precomputed data; issue before the poll
    float4 dxv;
    if (tid < 512) dxv = *(const float4*)(dxp + (long)(r0 + r) * 4);

    // ---- per-wave poll: 16 producer-block flags (one 64 B line), no RMW ----
    unsigned fv = (unsigned)e;
    for (;;) {
      if (lane < 16)
        fv = __hip_atomic_load(bar + 16 * w + lane,
                               __ATOMIC_RELAXED, __HIP_MEMORY_SCOPE_AGENT);
      if (__all((int)(fv >= (unsigned)e))) break;
      __builtin_amdgcn_s_sleep(2);
    }
    const unsigned dep = fv >> 31;   // 0 at runtime; data-dep into load addresses

    // ---- MFMA: zn = adj @ z over K-slice [w*256,+256) via IC atomic loads ----
    f32x4 a0 = {0.f, 0.f, 0.f, 0.f}, a1 = {0.f, 0.f, 0.f, 0.f};
    const u64* bq = (const u64*)zi + (size_t)w * 1024 + (lane << 1) + dep;
    bfrag bf[8];
#pragma unroll
    for (int i = 0; i < 8; ++i) {
      bf[i].q[0] = __hip_atomic_load(bq + i * 128,
                                     __ATOMIC_RELAXED, __HIP_MEMORY_SCOPE_AGENT);
      bf[i].q[1] = __hip_atomic_load(bq + i * 128 + 1,
                                     __ATOMIC_RELAXED, __HIP_MEMORY_SCOPE_AGENT);
    }
#pragma unroll
    for (int i = 0; i < 8; ++i)
      a0 = __builtin_amdgcn_mfma_f32_16x16x32_bf16(av[i], bf[i].s8, a0, 0, 0, 0);
#pragma unroll
    for (int i = 0; i < 8; ++i) {
      bf[i].q[0] = __hip_atomic_load(bq + 16384 + i * 128,
                                     __ATOMIC_RELAXED, __HIP_MEMORY_SCOPE_AGENT);
      bf[i].q[1] = __hip_atomic_load(bq + 16384 + i * 128 + 1,
                                     __ATOMIC_RELAXED, __HIP_MEMORY_SCOPE_AGENT);
    }
#pragma unroll
    for (int i = 0; i < 8; ++i)
      a1 = __builtin_amdgcn_mfma_f32_16x16x32_bf16(av[i], bf[i].s8, a1, 0, 0, 0);

    {
      const int crow = (lane >> 4) * 4, ccol = lane & 15;  // C/D: col=lane&15
#pragma unroll
      for (int q = 0; q < 4; ++q) {
        red2[crow + q][ccol][w] = a0[q];
        red2[crow + q][ccol + 16][w] = a1[q];
      }
    }
    __syncthreads();                       // B1: red2 complete

    // ---- cross-wave K-reduction (waves 0-7); decoder on waves 8-11 ----
    if (tid < 512) {
      float zn = 0.f;
#pragma unroll
      for (int q = 0; q < 16; ++q) zn += red2[r][c][q];
      zn_s[r][c] = zn;
    } else if (j == 1 && e > 1 && tid < 768) {
      // zb_s holds z_tt (stable this epoch; j==1 einsum doesn't write it)
      dec_rows(&zb_s[0][0], &Wd1_s[0][0], dsm, out + tt * NN, r0, tid - 512);
    }
    __syncthreads();                       // B2: zn_s complete, red2 free

    // ---- h = relu(zn@Wg + ze@Wt + bg + bt) ----
    if (tid < 512) {
      float hv = bgt_s[c];
#pragma unroll
      for (int kk = 0; kk < 32; ++kk)
        hv = fmaf(zn_s[r][kk], Wg_s[kk][c], fmaf(ze_s[r][kk], Wt_s[kk][c], hv));
      h_s[r][c] = fmaxf(hv, 0.f);
    }
    __syncthreads();                       // B3: h_s complete

    // ---- sens/einsum + RK4 update + per-wave publish (no barrier, no RMW) ----
    if (tid < 512) {
      float s0 = bp_s[c * 4], s1 = bp_s[c * 4 + 1];
      float s2 = bp_s[c * 4 + 2], s3 = bp_s[c * 4 + 3];
#pragma unroll
      for (int hp = 0; hp < 32; ++hp) {
        const float4 wv = *(const float4*)&Wp_s[hp][c * 4];
        const float hr = h_s[r][hp];
        s0 = fmaf(hr, wv.x, s0);
        s1 = fmaf(hr, wv.y, s1);
        s2 = fmaf(hr, wv.z, s2);
        s3 = fmaf(hr, wv.w, s3);
      }
      const float kv = s0 * dxv.x + s1 * dxv.y + s2 * dxv.z + s3 * dxv.w;
      float zev;
      if (j == 1)      { ka_s[r][c] = kv;            zev = zb_s[r][c] + 0.5f * kv; }
      else if (j == 2) { ka_s[r][c] += 2.f * kv;     zev = zb_s[r][c] + 0.5f * kv; }
      else if (j == 3) { ka_s[r][c] += 2.f * kv;     zev = zb_s[r][c] + kv; }
      else { zev = zb_s[r][c] + (ka_s[r][c] + kv) * (1.f / 6.f); zb_s[r][c] = zev; }
      ze_s[r][c] = zev;

      // publish this wave's 2 rows straight from registers; last wave flags
      const float zhi = __shfl_down(zev, 32);
      if (lane < 32)
        __hip_atomic_store((unsigned*)zo + (zt_idx(r0 + 2 * w, lane) >> 1),
                           pack2(zev, zhi),
                           __ATOMIC_RELAXED, __HIP_MEMORY_SCOPE_AGENT);
      if (lane == 0) {
        asm volatile("s_waitcnt vmcnt(0)" ::: "memory");
        const unsigned old = atomicAdd(&lcnt, 1u);
        if (old == 8u * (unsigned)(e + 1) - 1u)
          __hip_atomic_store(bar + bid, (unsigned)(e + 1),
                             __ATOMIC_RELAXED, __HIP_MEMORY_SCOPE_AGENT);
      }
    }
  }

  // ---- final decode: z_15 ----
  __syncthreads();
  if (tid < 256) dec_rows(&zb_s[0][0], &Wd1_s[0][0], dsm, out + 15 * NN, r0, tid);
}

extern "C" void kernel_launch(void* const* d_in, const int* in_sizes, int n_in,
                              void* d_out, int out_size, void* d_ws, size_t ws_size,
                              hipStream_t stream) {
  (void)in_sizes; (void)n_in; (void)out_size; (void)ws_size;
  const float* x      = (const float*)d_in[0];
  const float* adj    = (const float*)d_in[1];
  const float* W_enc  = (const float*)d_in[2];
  const float* b_enc  = (const float*)d_in[3];
  const float* W_gcn  = (const float*)d_in[4];
  const float* b_gcn  = (const float*)d_in[5];
  const float* W_time = (const float*)d_in[6];
  const float* b_time = (const float*)d_in[7];
  const float* W_proj = (const float*)d_in[8];
  const float* b_proj = (const float*)d_in[9];
  const float* W_d1   = (const float*)d_in[10];
  const float* b_d1   = (const float*)d_in[11];
  const float* W_d2   = (const float*)d_in[12];
  const float* b_d2   = (const float*)d_in[13];
  float* out = (float*)d_out;

  float* dx0 = (float*)d_ws;
  float* dxh = dx0 + 15 * NI;
  float* dx1 = dxh + 15 * NI;
  short* zTa = (short*)(dx1 + 15 * NI);
  short* zTb = zTa + HH * NN;
  unsigned* bar = (unsigned*)(zTb + HH * NN);   // 256 per-block flags (+pad)

  k_spline<<<64, 256, 0, stream>>>(x, dx0, dxh, dx1, bar);

  void* args[] = {(void*)&adj, (void*)&x, (void*)&dx0, (void*)&dxh, (void*)&dx1,
                  (void*)&W_enc, (void*)&b_enc, (void*)&W_gcn, (void*)&b_gcn,
                  (void*)&W_time, (void*)&b_time, (void*)&W_proj, (void*)&b_proj,
                  (void*)&W_d1, (void*)&b_d1, (void*)&W_d2, (void*)&b_d2,
                  (void*)&zTa, (void*)&zTb, (void*)&bar, (void*)&out};
  hipError_t err = hipLaunchCooperativeKernel((const void*)k_ode, dim3(256),
                                              dim3(1024), args, 0, stream);
  if (err != hipSuccess) {
    // Fallback only; cooperative is required to guarantee the spin loops
    // cannot be preempted (r6 plain launch showed a 21.5 ms stall).
    k_ode<<<256, 1024, 0, stream>>>(adj, x, dx0, dxh, dx1, W_enc, b_enc,
                                    W_gcn, b_gcn, W_time, b_time, W_proj, b_proj,
                                    W_d1, b_d1, W_d2, b_d2, zTa, zTb, bar, out);
  }
}

// Round 8
// 751.368 us; speedup vs baseline: 1.4758x; 1.1638x over previous
//
#include <hip/hip_runtime.h>
#include <hip/hip_bf16.h>

#define NN 4096
#define NI 16384   // N*I
#define HH 32

typedef __attribute__((ext_vector_type(8))) short short8;
typedef __attribute__((ext_vector_type(4))) float f32x4;
typedef unsigned long long u64;

union bfrag { short8 s8; u64 q[2]; };

__device__ __forceinline__ short f2bs(float f) {
  __hip_bfloat16 b = __float2bfloat16(f);
  return *(short*)&b;
}

__device__ __forceinline__ unsigned pack2(float lo, float hi) {
  return (unsigned)(unsigned short)f2bs(lo) |
         ((unsigned)(unsigned short)f2bs(hi) << 16);
}

// zT B-fragment layout: element z[n][h] at short index
//   ((hb*128 + kb)*64 + hl + 16*oct)*8 + j  (hb=h>>4, hl=h&15, kb=n>>5, oct=(n>>3)&3, j=n&7)
__device__ __forceinline__ long zt_idx(int n, int h) {
  const int hb = h >> 4, hl = h & 15;
  const int kb = n >> 5, oct = (n >> 3) & 3, j = n & 7;
  return ((long)(hb * 128 + kb) * 64 + hl + 16 * oct) * 8 + j;
}

// ---------------- natural cubic spline -> dX/dt at s=0, 0.5, 1 ----------------
// Also zero-inits the grid-barrier state (replay-safe: reruns every graph replay).
__global__ void k_spline(const float* __restrict__ x,
                         float* __restrict__ dx0, float* __restrict__ dxh,
                         float* __restrict__ dx1, unsigned* __restrict__ bar) {
  if (blockIdx.x == 0) {
    for (int i = threadIdx.x; i < 576; i += 256) bar[i] = 0u;
    // layout: group counters at g*32 (g<16), root at 512
  }
  const int c = blockIdx.x * 256 + threadIdx.x;
  float y[16];
#pragma unroll
  for (int t = 0; t < 16; ++t) y[t] = x[t * NI + c];
  float cp[15], dp[15], M[16];
  cp[1] = 0.25f;
  dp[1] = (6.f * (y[2] - 2.f * y[1] + y[0])) * 0.25f;
#pragma unroll
  for (int i = 2; i <= 14; ++i) {
    float ri = 6.f * (y[i + 1] - 2.f * y[i] + y[i - 1]);
    float inv = 1.f / (4.f - cp[i - 1]);
    cp[i] = inv;
    dp[i] = (ri - dp[i - 1]) * inv;
  }
  M[0] = 0.f; M[15] = 0.f;
  M[14] = dp[14];
#pragma unroll
  for (int i = 13; i >= 1; --i) M[i] = dp[i] - cp[i] * M[i + 1];
#pragma unroll
  for (int i = 0; i < 15; ++i) {
    float b = (y[i + 1] - y[i]) - (2.f * M[i] + M[i + 1]) * (1.f / 6.f);
    float cc = 0.5f * M[i];
    float dd = (M[i + 1] - M[i]) * (1.f / 6.f);
    dx0[i * NI + c] = b;
    dxh[i * NI + c] = b + cc + 0.75f * dd;
    dx1[i * NI + c] = b + 2.f * cc + 3.f * dd;
  }
}

// ---- two-level grid barrier: NO cache maintenance at all.
// Release: WT agent-scope atomic stores, drained by each wave's vmcnt(0) at
// __syncthreads -> acked at IC before lane0's arrival add.
// Acquire: readers touch mutable data ONLY via agent-scope atomic loads (IC
// endpoint), so no L2/L1 invalidate is needed.
__device__ __forceinline__ void gridbar(unsigned* bar, int bid, int e) {
  __syncthreads();   // each wave drains vmcnt(0): its WT stores are acked at IC
  if (threadIdx.x == 0) {
    unsigned old = __hip_atomic_fetch_add(bar + (bid & 7) * 32, 1u,
                                          __ATOMIC_RELAXED, __HIP_MEMORY_SCOPE_AGENT);
    if (old == (unsigned)(32 * e - 1)) {          // last of my 32-block group
      unsigned rr = __hip_atomic_fetch_add(bar + 256, 1u,
                                           __ATOMIC_RELAXED, __HIP_MEMORY_SCOPE_AGENT);
      if (rr == (unsigned)(8 * e - 1)) {          // last group: broadcast to 8 flags
#pragma unroll
        for (int g = 0; g < 8; ++g)
          __hip_atomic_store(bar + 320 + g * 32, (unsigned)e,
                             __ATOMIC_RELAXED, __HIP_MEMORY_SCOPE_AGENT);
      }
    }
    while (__hip_atomic_load(bar + 320 + (bid & 7) * 32, __ATOMIC_RELAXED,
                             __HIP_MEMORY_SCOPE_AGENT) < (unsigned)e)
      __builtin_amdgcn_s_sleep(2);
  }
  __syncthreads();   // compiler+hw barrier: no wave issues next-epoch reads early
}

// ---- decoder for one 16-row block: 256 threads, (r,jj) each 32 FMA + 16-lane reduce ----
__device__ __forceinline__ void dec_block(const float* zsrc /*[16][33]*/,
                                          const float* Wd1s /*[32][16]*/,
                                          const float* dsm, float* op,
                                          int r0, int tid) {
  if (tid < 256) {
    const int rr = tid >> 4, jj = tid & 15;
    float hv = dsm[jj];
#pragma unroll
    for (int hh = 0; hh < 32; ++hh) hv = fmaf(zsrc[rr * 33 + hh], Wd1s[hh * 16 + jj], hv);
    float val = fmaxf(hv, 0.f) * dsm[16 + jj];
#pragma unroll
    for (int off = 1; off < 16; off <<= 1) val += __shfl_xor(val, off, 64);
    if (jj == 0)
      __hip_atomic_store(op + r0 + rr, 1.f / (1.f + expf(-(dsm[32] + val))),
                         __ATOMIC_RELAXED, __HIP_MEMORY_SCOPE_AGENT);
  }
}

// ---------------- persistent full-integration kernel ----------------
// 256 blocks x 1024 threads (16 waves), 1 block/CU, cooperative.
// Each block owns rows [r0, r0+16); its adj slice (128 KB bf16) lives in
// VGPRs (8 x short8 = 32 VGPR/thread) for ALL 60 vector-field evals.
__global__ __launch_bounds__(1024, 4) void k_ode(
    const float* __restrict__ adj, const float* __restrict__ x,
    const float* __restrict__ dx0, const float* __restrict__ dxh,
    const float* __restrict__ dx1,
    const float* __restrict__ We, const float* __restrict__ be,
    const float* __restrict__ Wg, const float* __restrict__ bg,
    const float* __restrict__ Wt, const float* __restrict__ bt,
    const float* __restrict__ Wp, const float* __restrict__ bp,
    const float* __restrict__ Wd1, const float* __restrict__ bd1,
    const float* __restrict__ Wd2, const float* __restrict__ bd2,
    short* __restrict__ zTa, short* __restrict__ zTb,
    unsigned* __restrict__ bar, float* __restrict__ out) {
  __shared__ float red2[16][34][17];   // cross-wave MFMA partials; stride 578≡2 mod 32
  __shared__ float zn_s[16][33];
  __shared__ float h_s[16][33];
  __shared__ float ze_s[16][33];       // z at which vf is evaluated (f32)
  __shared__ float zb_s[16][33];       // RK4 base z
  __shared__ float ka_s[16][33];       // k1 + 2k2 + 2k3 accumulator
  __shared__ float Wg_s[32][32];
  __shared__ float Wt_s[32][32];
  __shared__ float Wp_s[32][136];      // row stride 544 B, float4-readable
  __shared__ float Wd1_s[32][16];
  __shared__ float bgt_s[32];
  __shared__ float bp_s[128];
  __shared__ float dsm[33];            // b_d1[0:16], W_d2[16:32], b_d2[32]

  const int tid = threadIdx.x;
  const int lane = tid & 63;
  const int w = tid >> 6;              // wave 0..15
  const int bid = blockIdx.x;
  const int r0 = bid * 16;
  const int fr = lane & 15, oct = lane >> 4;

  // ---- adj -> registers, bf16 A-fragment order (once, ~64 MB grid-wide) ----
  short8 av[8];
  {
    const float* arow = adj + (long)(r0 + fr) * NN + w * 256 + oct * 8;
#pragma unroll
    for (int i = 0; i < 8; ++i) {
      const float4 u0 = *(const float4*)(arow + i * 32);
      const float4 u1 = *(const float4*)(arow + i * 32 + 4);
      short8 rf;
      rf[0] = f2bs(u0.x); rf[1] = f2bs(u0.y); rf[2] = f2bs(u0.z); rf[3] = f2bs(u0.w);
      rf[4] = f2bs(u1.x); rf[5] = f2bs(u1.y); rf[6] = f2bs(u1.z); rf[7] = f2bs(u1.w);
      av[i] = rf;
    }
  }

  // ---- stage weights into LDS (once for all 60 evals) ----
  Wg_s[tid >> 5][tid & 31] = Wg[tid];
  Wt_s[tid >> 5][tid & 31] = Wt[tid];
#pragma unroll
  for (int idx = tid; idx < 4096; idx += 1024)
    Wp_s[idx >> 7][idx & 127] = Wp[idx];
  if (tid < 512) Wd1_s[tid >> 4][tid & 15] = Wd1[tid];
  if (tid < 32) bgt_s[tid] = bg[tid] + bt[tid];
  if (tid < 128) bp_s[tid] = bp[tid];
  if (tid < 16) { dsm[tid] = bd1[tid]; dsm[16 + tid] = Wd2[tid]; }
  if (tid == 0) dsm[32] = bd2[0];

  // ---- encoder: z0 for this block's 16 rows ----
  const int r = (tid >> 5) & 15, c = tid & 31;
  if (tid < 512) {
    const int n = r0 + r;
    float acc = be[c];
#pragma unroll
    for (int i = 0; i < 4; ++i) acc = fmaf(x[n * 4 + i], We[i * 32 + c], acc);
    zb_s[r][c] = acc;
    ze_s[r][c] = acc;
  }
  __syncthreads();
  // pack z0 -> zTa as WT u64 atomics (wave 4-5 range); decode t=0 (waves 0-3)
  if (tid >= 256 && tid < 384) {
    const int q = tid - 256;
    const int cc = q & 31, rr = (q >> 5) * 4;
    const u64 pk = (u64)pack2(ze_s[rr][cc], ze_s[rr + 1][cc]) |
                   ((u64)pack2(ze_s[rr + 2][cc], ze_s[rr + 3][cc]) << 32);
    __hip_atomic_store((u64*)zTa + (zt_idx(r0 + rr, cc) >> 2), pk,
                       __ATOMIC_RELAXED, __HIP_MEMORY_SCOPE_AGENT);
  }
  dec_block(&zb_s[0][0], &Wd1_s[0][0], dsm, out, r0, tid);   // t=0 output

  int ep = 0;
  gridbar(bar, bid, ++ep);             // zTa fully visible grid-wide

  const short* zi = zTa;
  short* zo = zTb;

  for (int t = 0; t < 15; ++t) {
    const float* dt0 = dx0 + t * NI;
    const float* dth = dxh + t * NI;
    const float* dt1 = dx1 + t * NI;
    for (int j = 1; j <= 4; ++j) {
      const float* dxp = (j == 1) ? dt0 : (j == 4) ? dt1 : dth;

      // dx row: read-only, L1/L2-warm (never invalidated)
      float4 dxv;
      if (tid < 512) dxv = *(const float4*)(dxp + (long)(r0 + r) * 4);

      // ---- MFMA: zn = adj @ z ; adj from regs, z frags via agent-scope
      // atomic u64 loads (IC endpoint -> always fresh, no cache maintenance).
      // Stage 8 fragments (16 loads) before consuming: one IC round-trip/half.
      f32x4 a0 = {0.f, 0.f, 0.f, 0.f}, a1 = {0.f, 0.f, 0.f, 0.f};
      const u64* bq = (const u64*)zi + (size_t)w * 1024 + (lane << 1);
      bfrag bf[8];
#pragma unroll
      for (int i = 0; i < 8; ++i) {
        bf[i].q[0] = __hip_atomic_load(bq + i * 128,
                                       __ATOMIC_RELAXED, __HIP_MEMORY_SCOPE_AGENT);
        bf[i].q[1] = __hip_atomic_load(bq + i * 128 + 1,
                                       __ATOMIC_RELAXED, __HIP_MEMORY_SCOPE_AGENT);
      }
#pragma unroll
      for (int i = 0; i < 8; ++i)
        a0 = __builtin_amdgcn_mfma_f32_16x16x32_bf16(av[i], bf[i].s8, a0, 0, 0, 0);
#pragma unroll
      for (int i = 0; i < 8; ++i) {
        bf[i].q[0] = __hip_atomic_load(bq + 16384 + i * 128,
                                       __ATOMIC_RELAXED, __HIP_MEMORY_SCOPE_AGENT);
        bf[i].q[1] = __hip_atomic_load(bq + 16384 + i * 128 + 1,
                                       __ATOMIC_RELAXED, __HIP_MEMORY_SCOPE_AGENT);
      }
#pragma unroll
      for (int i = 0; i < 8; ++i)
        a1 = __builtin_amdgcn_mfma_f32_16x16x32_bf16(av[i], bf[i].s8, a1, 0, 0, 0);

      {
        const int crow = (lane >> 4) * 4, ccol = lane & 15;  // C/D: col=lane&15
#pragma unroll
        for (int q = 0; q < 4; ++q) {
          red2[crow + q][ccol][w] = a0[q];
          red2[crow + q][ccol + 16][w] = a1[q];
        }
      }
      __syncthreads();

      // ---- cross-wave K-reduction ----
      if (tid < 512) {
        float zn = 0.f;
#pragma unroll
        for (int q = 0; q < 16; ++q) zn += red2[r][c][q];
        zn_s[r][c] = zn;
      }
      __syncthreads();

      // ---- h = relu(zn@Wg + ze@Wt + bg + bt) ----
      if (tid < 512) {
        float hv = bgt_s[c];
#pragma unroll
        for (int kk = 0; kk < 32; ++kk)
          hv = fmaf(zn_s[r][kk], Wg_s[kk][c], fmaf(ze_s[r][kk], Wt_s[kk][c], hv));
        h_s[r][c] = fmaxf(hv, 0.f);
      }
      __syncthreads();

      // ---- sens/einsum + RK4 state update (all in LDS) ----
      if (tid < 512) {
        float s0 = bp_s[c * 4], s1 = bp_s[c * 4 + 1];
        float s2 = bp_s[c * 4 + 2], s3 = bp_s[c * 4 + 3];
#pragma unroll
        for (int hp = 0; hp < 32; ++hp) {
          const float4 wv = *(const float4*)&Wp_s[hp][c * 4];
          const float hr = h_s[r][hp];
          s0 = fmaf(hr, wv.x, s0);
          s1 = fmaf(hr, wv.y, s1);
          s2 = fmaf(hr, wv.z, s2);
          s3 = fmaf(hr, wv.w, s3);
        }
        const float kv = s0 * dxv.x + s1 * dxv.y + s2 * dxv.z + s3 * dxv.w;
        float zev;
        if (j == 1)      { ka_s[r][c] = kv;            zev = zb_s[r][c] + 0.5f * kv; }
        else if (j == 2) { ka_s[r][c] += 2.f * kv;     zev = zb_s[r][c] + 0.5f * kv; }
        else if (j == 3) { ka_s[r][c] += 2.f * kv;     zev = zb_s[r][c] + kv; }
        else { zev = zb_s[r][c] + (ka_s[r][c] + kv) * (1.f / 6.f); zb_s[r][c] = zev; }
        ze_s[r][c] = zev;
      }
      __syncthreads();                 // ze_s (and zb_s for j==4) complete

      // pack new z -> zo as WT u64 atomics; decode (waves 0-3) runs concurrently
      if (tid >= 256 && tid < 384) {
        const int q = tid - 256;
        const int cc = q & 31, rr = (q >> 5) * 4;
        const u64 pk = (u64)pack2(ze_s[rr][cc], ze_s[rr + 1][cc]) |
                       ((u64)pack2(ze_s[rr + 2][cc], ze_s[rr + 3][cc]) << 32);
        __hip_atomic_store((u64*)zo + (zt_idx(r0 + rr, cc) >> 2), pk,
                           __ATOMIC_RELAXED, __HIP_MEMORY_SCOPE_AGENT);
      }
      if (j == 4)
        dec_block(&zb_s[0][0], &Wd1_s[0][0], dsm, out + (t + 1) * NN, r0, tid);

      gridbar(bar, bid, ++ep);         // zo visible grid-wide; prev reads done
      const short* tz = zi; zi = zo; zo = (short*)tz;
    }
  }
}

extern "C" void kernel_launch(void* const* d_in, const int* in_sizes, int n_in,
                              void* d_out, int out_size, void* d_ws, size_t ws_size,
                              hipStream_t stream) {
  (void)in_sizes; (void)n_in; (void)out_size; (void)ws_size;
  const float* x      = (const float*)d_in[0];
  const float* adj    = (const float*)d_in[1];
  const float* W_enc  = (const float*)d_in[2];
  const float* b_enc  = (const float*)d_in[3];
  const float* W_gcn  = (const float*)d_in[4];
  const float* b_gcn  = (const float*)d_in[5];
  const float* W_time = (const float*)d_in[6];
  const float* b_time = (const float*)d_in[7];
  const float* W_proj = (const float*)d_in[8];
  const float* b_proj = (const float*)d_in[9];
  const float* W_d1   = (const float*)d_in[10];
  const float* b_d1   = (const float*)d_in[11];
  const float* W_d2   = (const float*)d_in[12];
  const float* b_d2   = (const float*)d_in[13];
  float* out = (float*)d_out;

  float* dx0 = (float*)d_ws;
  float* dxh = dx0 + 15 * NI;
  float* dx1 = dxh + 15 * NI;
  short* zTa = (short*)(dx1 + 15 * NI);
  short* zTb = zTa + HH * NN;
  unsigned* bar = (unsigned*)(zTb + HH * NN);   // 576 u32 of barrier state

  k_spline<<<64, 256, 0, stream>>>(x, dx0, dxh, dx1, bar);

  void* args[] = {(void*)&adj, (void*)&x, (void*)&dx0, (void*)&dxh, (void*)&dx1,
                  (void*)&W_enc, (void*)&b_enc, (void*)&W_gcn, (void*)&b_gcn,
                  (void*)&W_time, (void*)&b_time, (void*)&W_proj, (void*)&b_proj,
                  (void*)&W_d1, (void*)&b_d1, (void*)&W_d2, (void*)&b_d2,
                  (void*)&zTa, (void*)&zTb, (void*)&bar, (void*)&out};
  hipError_t err = hipLaunchCooperativeKernel((const void*)k_ode, dim3(256),
                                              dim3(1024), args, 0, stream);
  if (err != hipSuccess) {
    // Fallback: grid == CU count with 16 waves/block fits exactly; all blocks
    // are dispatched at launch, so the spin barrier remains safe in practice.
    k_ode<<<256, 1024, 0, stream>>>(adj, x, dx0, dxh, dx1, W_enc, b_enc,
                                    W_gcn, b_gcn, W_time, b_time, W_proj, b_proj,
                                    W_d1, b_d1, W_d2, b_d2, zTa, zTb, bar, out);
  }
}